// Round 8
// baseline (266.633 us; speedup 1.0000x reference)
//
#include <hip/hip_runtime.h>

// DepthDeformConvPack on MI355X — round 12: 2 blocks/CU via BN=32 px split.
// r11 post-mortem (108us, best): WRITE clean (16.4MB) but conflicts UNCHANGED
// (12.66M vs 12.83M) -> the inter-group padding theory was wrong; conflicts
// are intrinsic to jittered strip reads + b128 param reads. Real remaining
// cost: phase serialization at 1 block/CU (occupancy 20%, VALU 29%, LDS pipe
// ~28% -> nothing overlaps the barrier-split stage/MFMA/gather phases).
// Changes (K3 only):
//   (a) BN 64->32 px, grid 512 = 2 blocks/CU (4 waves/SIMD). px-split does
//       NOT duplicate gather work (cout-split would); r5's BN=32 failure was
//       the GLOBAL gather (L1-bound, halving px didn't halve lines) — the
//       LDS gather halves per-block work for real.
//   (b) strip window 32->28 rows (±13 = 4.9 sigma, ~1 bad lane-tap/launch,
//       exact cold path) so LDS = 9x7280 strip + Bs/pwT/piT halved = 75.9KB
//       <= 80KB -> 2 blocks/CU. __launch_bounds__(512,4).
//   (c) per-lane gather = k-quad (4 piT + 4 pwT + 8 strip b64 + int2 write).
// Staging stays global_load_lds (r9/r10 proved reg-staging => scratch).

typedef __bf16 bf16x8 __attribute__((ext_vector_type(8)));
typedef float f32x4 __attribute__((ext_vector_type(4)));
typedef float float2_u __attribute__((ext_vector_type(2), aligned(4)));

__device__ __forceinline__ unsigned short f2bf(float f) {
  unsigned b = __float_as_uint(f);
  return (unsigned short)((b + 0x7fffu + ((b >> 16) & 1u)) >> 16);
}

// ---------------------------------------------------------------------------
// K0: weight fp32 -> bf16, natural layout (k = c*9+tap is already channel-major)
// ---------------------------------------------------------------------------
__global__ __launch_bounds__(256) void k_prep_weight(
    const float* __restrict__ w, unsigned short* __restrict__ wbf)
{
  const int i = blockIdx.x * 256 + threadIdx.x;   // grid 2304 -> 589824
  wbf[i] = f2bf(w[i]);
}

// ---------------------------------------------------------------------------
// K1: offset conv. grid = 4 ch-segments x (n,ho)=256 -> 1024 blocks, 256 thr.
// ---------------------------------------------------------------------------
__global__ __launch_bounds__(256) void k_offset_conv(
    const float* __restrict__ x, const float* __restrict__ depth,
    const float* __restrict__ off_w, const float* __restrict__ off_b,
    float* __restrict__ offs)
{
  const int seg = blockIdx.x >> 8;        // 0..3
  const int nh  = blockIdx.x & 255;
  const int n = nh >> 6, ho = nh & 63;
  const int tid = threadIdx.x;
  const int lane = tid & 63;              // == wo
  const int wave = tid >> 6;

  float acc[18];
#pragma unroll
  for (int i = 0; i < 18; ++i) acc[i] = 0.f;

  const int c0 = __builtin_amdgcn_readfirstlane(seg * 80 + wave * 20);

  for (int ci = 0; ci < 20; ++ci) {
    const int c = c0 + ci;
    const float* p = (c < 256) ? (x + (((n << 8) + c) << 12))
                               : (depth + (((n << 6) + (c - 256)) << 12));
    const float v0 = (ho > 0)  ? p[((ho - 1) << 6) + lane] : 0.f;
    const float v1 =             p[( ho      << 6) + lane];
    const float v2 = (ho < 63) ? p[((ho + 1) << 6) + lane] : 0.f;

    float v[9];
#pragma unroll
    for (int ky = 0; ky < 3; ++ky) {
      const float r = (ky == 0) ? v0 : ((ky == 1) ? v1 : v2);
#pragma unroll
      for (int kx = 0; kx < 3; ++kx) {
        const int src = lane + kx - 1;
        const float s = __shfl(r, src & 63);
        v[ky * 3 + kx] = (src >= 0 && src < 64) ? s : 0.f;
      }
    }
    const float* wp = off_w + c * 9;   // wave-uniform address
#pragma unroll
    for (int co = 0; co < 18; ++co) {
      const float* w = wp + co * 2880;
#pragma unroll
      for (int t = 0; t < 9; ++t) acc[co] += v[t] * w[t];
    }
  }

  __shared__ float red[4][18][64];
#pragma unroll
  for (int co = 0; co < 18; ++co) red[wave][co][lane] = acc[co];
  __syncthreads();
  for (int o = tid; o < 18 * 64; o += 256) {
    const int co = o >> 6, wo = o & 63;
    float s = red[0][co][wo] + red[1][co][wo] + red[2][co][wo] + red[3][co][wo];
    if (seg == 0) s += off_b[co];
    atomicAdd(&offs[((n * 18 + co) << 12) + (ho << 6) + wo], s);
  }
}

// ---------------------------------------------------------------------------
// K2: mask deform conv on depth + sigmoid. 256 blocks (n,ho), 512 thr = 8 waves.
// ---------------------------------------------------------------------------
__global__ __launch_bounds__(512) void k_mask_conv(
    const float* __restrict__ depth, const float* __restrict__ offs,
    const float* __restrict__ mask_w, const float* __restrict__ mask_b,
    float* __restrict__ mask)
{
  const int n  = blockIdx.x >> 6;
  const int ho = blockIdx.x & 63;
  const int tid  = threadIdx.x;
  const int lane = tid & 63;          // wo
  const int wave = tid >> 6;          // 0..7
  const int wo = lane;

  int i00[9], i01[9], i10[9], i11[9];
  float cw00[9], cw01[9], cw10[9], cw11[9];
  const float* op = offs + ((n * 18) << 12) + (ho << 6) + wo;
#pragma unroll
  for (int k = 0; k < 9; ++k) {
    const float dy = op[(2 * k) << 12];
    const float dx = op[(2 * k + 1) << 12];
    const float yy = (float)(ho - 1 + k / 3) + dy;
    const float xx = (float)(wo - 1 + k % 3) + dx;
    const float y0f = floorf(yy), x0f = floorf(xx);
    const float ly = yy - y0f, lx = xx - x0f;
    const int y0 = (int)y0f, x0 = (int)x0f;
    const int y0c = min(max(y0, 0), 63),     x0c = min(max(x0, 0), 63);
    const int y1c = min(max(y0 + 1, 0), 63), x1c = min(max(x0 + 1, 0), 63);
    const float fy0 = (y0 >= 0 && y0 < 64) ? 1.f : 0.f;
    const float fy1 = (y0 >= -1 && y0 < 63) ? 1.f : 0.f;
    const float fx0 = (x0 >= 0 && x0 < 64) ? 1.f : 0.f;
    const float fx1 = (x0 >= -1 && x0 < 63) ? 1.f : 0.f;
    i00[k] = (y0c << 6) + x0c;  i01[k] = (y0c << 6) + x1c;
    i10[k] = (y1c << 6) + x0c;  i11[k] = (y1c << 6) + x1c;
    cw00[k] = (1.f - ly) * (1.f - lx) * fy0 * fx0;
    cw01[k] = (1.f - ly) * lx * fy0 * fx1;
    cw10[k] = ly * (1.f - lx) * fy1 * fx0;
    cw11[k] = ly * lx * fy1 * fx1;
  }

  float acc[9];
#pragma unroll
  for (int i = 0; i < 9; ++i) acc[i] = 0.f;

  const int cbase = __builtin_amdgcn_readfirstlane(wave * 8);
  for (int cc = 0; cc < 8; ++cc) {
    const int c = cbase + cc;
    const float* p = depth + (((n << 6) + c) << 12);
    float val[9];
#pragma unroll
    for (int k = 0; k < 9; ++k) {
      val[k] = p[i00[k]] * cw00[k] + p[i01[k]] * cw01[k] +
               p[i10[k]] * cw10[k] + p[i11[k]] * cw11[k];
    }
    const float* wp = mask_w + c * 9;
#pragma unroll
    for (int co = 0; co < 9; ++co) {
#pragma unroll
      for (int k = 0; k < 9; ++k) acc[co] += val[k] * wp[co * 576 + k];
    }
  }

  __shared__ float red[8][9][64];
#pragma unroll
  for (int co = 0; co < 9; ++co) red[wave][co][lane] = acc[co];
  __syncthreads();
  for (int o = tid; o < 9 * 64; o += 512) {
    const int co = o >> 6, w2 = o & 63;
    float s = mask_b[co];
#pragma unroll
    for (int w = 0; w < 8; ++w) s += red[w][co][w2];
    mask[((n * 9 + co) << 12) + (ho << 6) + w2] = 1.f / (1.f + expf(-s));
  }
}

// ---------------------------------------------------------------------------
// K3: main modulated deform conv, bf16 MFMA GEMM, channel-major K.
// C[256co x 16384px] = Wbf[256 x 2304] * cols[2304 x px], k = c*9 + tap.
// Block: BN=32 px (half a row), BM=256, BK=64, 512 thr = 8 waves, grid 512
// -> 2 blocks/CU. x staged via global_load_lds into a 9-slot strip ring,
// 28 rows/channel as 7 linear 1024B groups at 1040B stride. Params in LDS
// tables [9][32] with precomputed padded byte offsets.
// ---------------------------------------------------------------------------
__device__ __forceinline__ void stage_channel_pad(const float* src, char* dstb,
                                                  int lane) {
  // 28 rows x 256B staged as 7 linear 1024B calls at 1040B LDS stride.
  const char* s = (const char*)src + lane * 16;
#pragma unroll
  for (int j = 0; j < 7; ++j)
    __builtin_amdgcn_global_load_lds(
        (const __attribute__((address_space(1))) void*)(s + j * 1024),
        (__attribute__((address_space(3))) void*)(dstb + j * 1040), 16, 0, 0);
}

__global__ __launch_bounds__(512, 4) void k_deform_gemm(
    const float* __restrict__ x, const float* __restrict__ offs,
    const float* __restrict__ mask, const unsigned short* __restrict__ wbf,
    const float* __restrict__ bias, float* __restrict__ out)
{
  __shared__ float strip[9 * 1820];                    // 9 x 7280 B = 65520 B
  __shared__ __align__(16) unsigned short Bs[32][72];  // 4608 B
  __shared__ float4 pwT[9][32];                        // 4608 B
  __shared__ int    piT[9][32];                        // 1152 B -> 75888 B

  const int tid = threadIdx.x;
  // XCD swizzle: b&7 = XCD; each XCD owns the 64 half-rows of a 32-row strip.
  const int b    = blockIdx.x;            // 512 blocks
  const int xcd  = b & 7, slot = b >> 3;  // slot 0..63
  const int n    = xcd >> 1;
  const int ho   = ((xcd & 1) << 5) + (slot >> 1);   // 0..63
  const int wo0  = (slot & 1) << 5;                  // 0 or 32
  const int pxb  = (ho << 6) + wo0;                  // px base within batch
  const int ylo  = min(max(ho - 13, 0), 36);         // strip rows [ylo, ylo+28)

  const int pxl  = tid & 31;        // px within block
  const int kq   = tid >> 5;        // 0..15 -> k-quad of 4
  const int oct  = tid >> 6;        // wave id 0..7 (staging)
  const int lane = tid & 63;
  const int mrow = lane & 15;
  const int koct = lane >> 4;       // 0..3 -> k-subgroup of 8
  const float* xn = x + ((long)(n << 8) << 12);
  const char* xnc = (const char*)xn;
  char* stripc = (char*)strip;

  // --- prologue: stage channels 0..7 (window of iter 0), one per wave
  stage_channel_pad(xn + (oct << 12) + (ylo << 6), stripc + oct * 7280, lane);
  int c_staged = 8;

  // --- phase 0: sampling params into LDS tables (e = tap*32 + px), tid<288
  if (tid < 288) {
    const int tap = tid >> 5, pl = tid & 31;
    const int wo = wo0 + pl;
    const float dy = offs[((n * 18 + 2 * tap) << 12) + pxb + pl];
    const float dx = offs[((n * 18 + 2 * tap + 1) << 12) + pxb + pl];
    const float m  = mask[((n * 9 + tap) << 12) + pxb + pl];
    const float yy = (float)(ho - 1 + tap / 3) + dy;
    const float xx = (float)(wo - 1 + tap % 3) + dx;
    const float y0f = floorf(yy), x0f = floorf(xx);
    const float ly = yy - y0f, lx = xx - x0f;
    const int y0 = (int)y0f, x0 = (int)x0f;
    const int y0c = min(max(y0, 0), 63);
    const int y1c = min(max(y0 + 1, 0), 63);
    const float fy0 = (y0 >= 0 && y0 < 64) ? 1.f : 0.f;
    const float fy1 = (y0 >= -1 && y0 < 63) ? 1.f : 0.f;
    // horizontal pair remap: contribution = wl*p[bx] + wr*p[bx+1]
    const int x0c = min(max(x0, 0), 63);
    const int x1c = min(max(x0 + 1, 0), 63);
    const int bx  = min(max(x0, 0), 62);
    const float vx0 = (x0 >= 0 && x0 < 64) ? 1.f : 0.f;
    const float vx1 = (x0 >= -1 && x0 < 63) ? 1.f : 0.f;
    const float wl = (1.f - lx) * vx0 * ((x0c == bx) ? 1.f : 0.f)
                   + lx * vx1 * ((x1c == bx) ? 1.f : 0.f);
    const float wr = (1.f - lx) * vx0 * ((x0c == bx + 1) ? 1.f : 0.f)
                   + lx * vx1 * ((x1c == bx + 1) ? 1.f : 0.f);
    const float a0 = (1.f - ly) * fy0 * m;
    const float a1 = ly * fy1 * m;
    pwT[tap][pl] = make_float4(wl * a0, wr * a0, wl * a1, wr * a1);
    // strip-relative byte addrs in the group-padded layout + bad flag:
    // ad = (ry>>2)*1040 + (ry&3)*256 + bx*4  (max 7256 < 16384)
    const int ry0 = y0c - ylo, ry1 = y1c - ylo;
    const int ry0c = min(max(ry0, 0), 27), ry1c = min(max(ry1, 0), 27);
    const int bad = ((ry0 != ry0c) || (ry1 != ry1c)) ? 1 : 0;
    const int ad0 = (ry0c >> 2) * 1040 + (ry0c & 3) * 256 + (bx << 2);
    const int ad1 = (ry1c >> 2) * 1040 + (ry1c & 3) * 256 + (bx << 2);
    piT[tap][pl] = ad0 | (ad1 << 14) | (bad << 28);
  }
  __syncthreads();   // params + prologue strip visible (barrier drains vmcnt)

  // --- gather: one k-quad (4 k) per lane into Bs; params from LDS tables.
  auto gather = [&](int ic) {
    const int k0 = (ic << 6) + (kq << 2);
    const int c0 = (int)(((unsigned)k0 * 7282u) >> 16);    // k0/9
    int tap = k0 - 9 * c0;
    const int s9 = (int)(((unsigned)c0 * 7282u) >> 16);    // c0/9
    int soff = (c0 - 9 * s9) * 7280;                       // slot byte offset

    __align__(8) unsigned short v[4];
    unsigned badm = 0;
#pragma unroll
    for (int j = 0; j < 4; ++j) {
      const int pk  = piT[tap][pxl];              // ds_read_b32
      const float4 w = pwT[tap][pxl];             // ds_read_b128
      const float2_u A = *(const float2_u*)(stripc + soff + (pk & 16383));
      const float2_u B = *(const float2_u*)(stripc + soff + ((pk >> 14) & 16383));
      v[j] = f2bf(A.x * w.x + A.y * w.y + B.x * w.z + B.y * w.w);
      badm |= ((unsigned)pk >> 28) << j;          // bit28 = bad; bits 29-31 = 0
      if (++tap == 9) {
        tap = 0;
        soff += 7280; if (soff == 9 * 7280) soff = 0;
      }
    }

    if (__builtin_expect(badm != 0, 0)) {         // ~1 lane-tap per launch
#pragma unroll
      for (int j = 0; j < 4; ++j) if (badm & (1u << j)) {
        const int k = k0 + j;
        const int c = (int)(((unsigned)k * 7282u) >> 16);
        const int tp = k - 9 * c;
        // full recompute from global (identical math to phase 0)
        const float dy = offs[((n * 18 + 2 * tp) << 12) + pxb + pxl];
        const float dx = offs[((n * 18 + 2 * tp + 1) << 12) + pxb + pxl];
        const float m  = mask[((n * 9 + tp) << 12) + pxb + pxl];
        const float yy = (float)(ho - 1 + tp / 3) + dy;
        const float xx = (float)(wo0 + pxl - 1 + tp % 3) + dx;
        const float y0f = floorf(yy), x0f = floorf(xx);
        const float ly = yy - y0f, lx = xx - x0f;
        const int y0 = (int)y0f, x0 = (int)x0f;
        const int y0c = min(max(y0, 0), 63);
        const int y1c = min(max(y0 + 1, 0), 63);
        const float fy0 = (y0 >= 0 && y0 < 64) ? 1.f : 0.f;
        const float fy1 = (y0 >= -1 && y0 < 63) ? 1.f : 0.f;
        const int x0c = min(max(x0, 0), 63);
        const int x1c = min(max(x0 + 1, 0), 63);
        const int bx  = min(max(x0, 0), 62);
        const float vx0 = (x0 >= 0 && x0 < 64) ? 1.f : 0.f;
        const float vx1 = (x0 >= -1 && x0 < 63) ? 1.f : 0.f;
        const float wl = (1.f - lx) * vx0 * ((x0c == bx) ? 1.f : 0.f)
                       + lx * vx1 * ((x1c == bx) ? 1.f : 0.f);
        const float wr = (1.f - lx) * vx0 * ((x0c == bx + 1) ? 1.f : 0.f)
                       + lx * vx1 * ((x1c == bx + 1) ? 1.f : 0.f);
        const float a0 = (1.f - ly) * fy0 * m;
        const float a1 = ly * fy1 * m;
        const char* pg = xnc + ((long)c << 14);
        const float2_u Ag = *(const float2_u*)(pg + (((y0c << 6) + bx) << 2));
        const float2_u Bg = *(const float2_u*)(pg + (((y1c << 6) + bx) << 2));
        v[j] = f2bf(Ag.x * (wl * a0) + Ag.y * (wr * a0) +
                    Bg.x * (wl * a1) + Bg.y * (wr * a1));
      }
    }
    *(int2*)&Bs[pxl][kq << 2] = *(const int2*)v;
  };

  // A-fragment prefetch registers for iter 0
  bf16x8 afc[2][2];
#pragma unroll
  for (int mt = 0; mt < 2; ++mt)
#pragma unroll
    for (int ks = 0; ks < 2; ++ks) {
      const int row = (oct << 5) + (mt << 4) + mrow;
      const int col = (ks << 5) + (koct << 3);
      afc[mt][ks] = *(const bf16x8*)(wbf + row * 2304 + col);
    }

  gather(0);
  __syncthreads();

  f32x4 acc[2][2];
#pragma unroll
  for (int mt = 0; mt < 2; ++mt)
#pragma unroll
    for (int nt = 0; nt < 2; ++nt)
#pragma unroll
      for (int r = 0; r < 4; ++r) acc[mt][nt][r] = 0.f;

  for (int ic = 0; ic < 36; ++ic) {
    // phase 1: stage next window (global_load_lds, overlaps MFMA; drained at
    // the barrier) + prefetch af(ic+1), MFMA(ic), barrier, gather(ic+1), barrier.
    if (ic < 35) {
      const int c_end = (64 * ic + 127) / 9;          // c_hi(ic+1) <= 255
      const int cw = c_staged + oct;
      if (cw <= c_end) {
        const int slt = cw - 9 * (int)(((unsigned)cw * 7282u) >> 16);
        stage_channel_pad(xn + (cw << 12) + (ylo << 6),
                          stripc + slt * 7280, lane);
      }
      c_staged = c_end + 1;
    }

    bf16x8 afn[2][2];
    if (ic < 35) {
      const int kc = (ic + 1) << 6;
#pragma unroll
      for (int mt = 0; mt < 2; ++mt)
#pragma unroll
        for (int ks = 0; ks < 2; ++ks) {
          const int row = (oct << 5) + (mt << 4) + mrow;
          const int col = kc + (ks << 5) + (koct << 3);
          afn[mt][ks] = *(const bf16x8*)(wbf + row * 2304 + col);
        }
    }

#pragma unroll
    for (int ks = 0; ks < 2; ++ks)
#pragma unroll
      for (int nt = 0; nt < 2; ++nt) {
        const bf16x8 bfr =
            *(const bf16x8*)&Bs[(nt << 4) + mrow][(ks << 5) + (koct << 3)];
        acc[0][nt] = __builtin_amdgcn_mfma_f32_16x16x32_bf16(afc[0][ks], bfr,
                                                             acc[0][nt], 0, 0, 0);
        acc[1][nt] = __builtin_amdgcn_mfma_f32_16x16x32_bf16(afc[1][ks], bfr,
                                                             acc[1][nt], 0, 0, 0);
      }

    __syncthreads();           // drains stage; Bs free for rewrite
    if (ic < 35) gather(ic + 1);
    __syncthreads();           // Bs ready for next MFMA; strip safe to restage

#pragma unroll
    for (int mt = 0; mt < 2; ++mt)
#pragma unroll
      for (int ks = 0; ks < 2; ++ks) afc[mt][ks] = afn[mt][ks];
  }

  // epilogue: C/D layout col=lane&15 (px), row=(lane>>4)*4+r (co)
#pragma unroll
  for (int mt = 0; mt < 2; ++mt)
#pragma unroll
    for (int nt = 0; nt < 2; ++nt)
#pragma unroll
      for (int r = 0; r < 4; ++r) {
        const int co = (oct << 5) + (mt << 4) + ((lane >> 4) << 2) + r;
        const int pxg = pxb + (nt << 4) + (lane & 15);
        out[(((n << 8) + co) << 12) + pxg] = acc[mt][nt][r] + bias[co];
      }
}

// ---------------------------------------------------------------------------
extern "C" void kernel_launch(void* const* d_in, const int* in_sizes, int n_in,
                              void* d_out, int out_size, void* d_ws, size_t ws_size,
                              hipStream_t stream) {
  const float* x      = (const float*)d_in[0];
  const float* depth  = (const float*)d_in[1];
  const float* weight = (const float*)d_in[2];
  const float* bias   = (const float*)d_in[3];
  const float* off_w  = (const float*)d_in[4];
  const float* off_b  = (const float*)d_in[5];
  const float* mask_w = (const float*)d_in[6];
  const float* mask_b = (const float*)d_in[7];
  float* out = (float*)d_out;

  float* offs = (float*)d_ws;                       // 294912 floats
  float* mask = offs + 294912;                      // 147456 floats
  unsigned short* wbf = (unsigned short*)(mask + 147456);  // 589824 bf16

  hipMemsetAsync(offs, 0, 294912 * sizeof(float), stream);
  k_prep_weight<<<2304, 256, 0, stream>>>(weight, wbf);
  k_offset_conv<<<1024, 256, 0, stream>>>(x, depth, off_w, off_b, offs);
  k_mask_conv<<<256, 512, 0, stream>>>(depth, offs, mask_w, mask_b, mask);
  k_deform_gemm<<<512, 512, 0, stream>>>(x, offs, mask, wbf, bias, out);
}

// Round 9
// 245.162 us; speedup vs baseline: 1.0876x; 1.0876x over previous
//
#include <hip/hip_runtime.h>

// DepthDeformConvPack on MI355X — round 13: revert K3 to r11; pair-load K2.
// r12 post-mortem (117.6us > r11's 108): 2nd occupancy experiment, 2nd null
// (occ 20->37%, conflicts unchanged 13.2M, dur WORSE) => K3 is LDS-pipe-
// throughput-bound; splitting px duplicated staging/params. K3 reverted to
// r11 exact (108us proven).
// New target: total - K3 == ~150us CONSTANT across all rounds (K0+K1+K2).
// Estimates: K1 VALU-bound ~13us, K0 ~3us => K2 ~50-60us: its gather does
// 8ch x 9tap x 4 SCALAR scattered loads/thread; lanes sample near x=lane
// with independent row jitter -> ~50+ lines per wave-instr -> ~127k cy/CU
// L1-tag cost. Fix: K3's proven horizontal pair remap (bx, folded weights,
// 2x float2_u row-pair loads) -> line-visits halve -> K2 ~27-30us.

typedef __bf16 bf16x8 __attribute__((ext_vector_type(8)));
typedef float f32x4 __attribute__((ext_vector_type(4)));
typedef float float2_u __attribute__((ext_vector_type(2), aligned(4)));

__device__ __forceinline__ unsigned short f2bf(float f) {
  unsigned b = __float_as_uint(f);
  return (unsigned short)((b + 0x7fffu + ((b >> 16) & 1u)) >> 16);
}

// ---------------------------------------------------------------------------
// K0: weight fp32 -> bf16, natural layout (k = c*9+tap is already channel-major)
// ---------------------------------------------------------------------------
__global__ __launch_bounds__(256) void k_prep_weight(
    const float* __restrict__ w, unsigned short* __restrict__ wbf)
{
  const int i = blockIdx.x * 256 + threadIdx.x;   // grid 2304 -> 589824
  wbf[i] = f2bf(w[i]);
}

// ---------------------------------------------------------------------------
// K1: offset conv. grid = 4 ch-segments x (n,ho)=256 -> 1024 blocks, 256 thr.
// ---------------------------------------------------------------------------
__global__ __launch_bounds__(256) void k_offset_conv(
    const float* __restrict__ x, const float* __restrict__ depth,
    const float* __restrict__ off_w, const float* __restrict__ off_b,
    float* __restrict__ offs)
{
  const int seg = blockIdx.x >> 8;        // 0..3
  const int nh  = blockIdx.x & 255;
  const int n = nh >> 6, ho = nh & 63;
  const int tid = threadIdx.x;
  const int lane = tid & 63;              // == wo
  const int wave = tid >> 6;

  float acc[18];
#pragma unroll
  for (int i = 0; i < 18; ++i) acc[i] = 0.f;

  const int c0 = __builtin_amdgcn_readfirstlane(seg * 80 + wave * 20);

  for (int ci = 0; ci < 20; ++ci) {
    const int c = c0 + ci;
    const float* p = (c < 256) ? (x + (((n << 8) + c) << 12))
                               : (depth + (((n << 6) + (c - 256)) << 12));
    const float v0 = (ho > 0)  ? p[((ho - 1) << 6) + lane] : 0.f;
    const float v1 =             p[( ho      << 6) + lane];
    const float v2 = (ho < 63) ? p[((ho + 1) << 6) + lane] : 0.f;

    float v[9];
#pragma unroll
    for (int ky = 0; ky < 3; ++ky) {
      const float r = (ky == 0) ? v0 : ((ky == 1) ? v1 : v2);
#pragma unroll
      for (int kx = 0; kx < 3; ++kx) {
        const int src = lane + kx - 1;
        const float s = __shfl(r, src & 63);
        v[ky * 3 + kx] = (src >= 0 && src < 64) ? s : 0.f;
      }
    }
    const float* wp = off_w + c * 9;   // wave-uniform address
#pragma unroll
    for (int co = 0; co < 18; ++co) {
      const float* w = wp + co * 2880;
#pragma unroll
      for (int t = 0; t < 9; ++t) acc[co] += v[t] * w[t];
    }
  }

  __shared__ float red[4][18][64];
#pragma unroll
  for (int co = 0; co < 18; ++co) red[wave][co][lane] = acc[co];
  __syncthreads();
  for (int o = tid; o < 18 * 64; o += 256) {
    const int co = o >> 6, wo = o & 63;
    float s = red[0][co][wo] + red[1][co][wo] + red[2][co][wo] + red[3][co][wo];
    if (seg == 0) s += off_b[co];
    atomicAdd(&offs[((n * 18 + co) << 12) + (ho << 6) + wo], s);
  }
}

// ---------------------------------------------------------------------------
// K2: mask deform conv on depth + sigmoid. 256 blocks (n,ho), 512 thr = 8 waves.
// Pair-load gather: per tap, 2x float2_u row-pair loads with folded weights
// (identical remap algebra to K3 phase 0, mask=1).
// ---------------------------------------------------------------------------
__global__ __launch_bounds__(512) void k_mask_conv(
    const float* __restrict__ depth, const float* __restrict__ offs,
    const float* __restrict__ mask_w, const float* __restrict__ mask_b,
    float* __restrict__ mask)
{
  const int n  = blockIdx.x >> 6;
  const int ho = blockIdx.x & 63;
  const int tid  = threadIdx.x;
  const int lane = tid & 63;          // wo
  const int wave = tid >> 6;          // 0..7
  const int wo = lane;

  int ia[9], ib[9];
  float w0[9], w1[9], w2c[9], w3[9];
  const float* op = offs + ((n * 18) << 12) + (ho << 6) + wo;
#pragma unroll
  for (int k = 0; k < 9; ++k) {
    const float dy = op[(2 * k) << 12];
    const float dx = op[(2 * k + 1) << 12];
    const float yy = (float)(ho - 1 + k / 3) + dy;
    const float xx = (float)(wo - 1 + k % 3) + dx;
    const float y0f = floorf(yy), x0f = floorf(xx);
    const float ly = yy - y0f, lx = xx - x0f;
    const int y0 = (int)y0f, x0 = (int)x0f;
    const int y0c = min(max(y0, 0), 63);
    const int y1c = min(max(y0 + 1, 0), 63);
    const float fy0 = (y0 >= 0 && y0 < 64) ? 1.f : 0.f;
    const float fy1 = (y0 >= -1 && y0 < 63) ? 1.f : 0.f;
    // horizontal pair remap (K3-proven): contribution = wl*p[bx] + wr*p[bx+1]
    const int x0c = min(max(x0, 0), 63);
    const int x1c = min(max(x0 + 1, 0), 63);
    const int bx  = min(max(x0, 0), 62);
    const float vx0 = (x0 >= 0 && x0 < 64) ? 1.f : 0.f;
    const float vx1 = (x0 >= -1 && x0 < 63) ? 1.f : 0.f;
    const float wl = (1.f - lx) * vx0 * ((x0c == bx) ? 1.f : 0.f)
                   + lx * vx1 * ((x1c == bx) ? 1.f : 0.f);
    const float wr = (1.f - lx) * vx0 * ((x0c == bx + 1) ? 1.f : 0.f)
                   + lx * vx1 * ((x1c == bx + 1) ? 1.f : 0.f);
    const float a0 = (1.f - ly) * fy0;
    const float a1 = ly * fy1;
    ia[k] = ((y0c << 6) + bx) << 2;     // byte offsets
    ib[k] = ((y1c << 6) + bx) << 2;
    w0[k] = wl * a0;  w1[k] = wr * a0;
    w2c[k] = wl * a1; w3[k] = wr * a1;
  }

  float acc[9];
#pragma unroll
  for (int i = 0; i < 9; ++i) acc[i] = 0.f;

  const int cbase = __builtin_amdgcn_readfirstlane(wave * 8);
  for (int cc = 0; cc < 8; ++cc) {
    const int c = cbase + cc;
    const char* p = (const char*)(depth + (((n << 6) + c) << 12));
    float val[9];
#pragma unroll
    for (int k = 0; k < 9; ++k) {
      const float2_u A = *(const float2_u*)(p + ia[k]);
      const float2_u B = *(const float2_u*)(p + ib[k]);
      val[k] = A.x * w0[k] + A.y * w1[k] + B.x * w2c[k] + B.y * w3[k];
    }
    const float* wp = mask_w + c * 9;
#pragma unroll
    for (int co = 0; co < 9; ++co) {
#pragma unroll
      for (int k = 0; k < 9; ++k) acc[co] += val[k] * wp[co * 576 + k];
    }
  }

  __shared__ float red[8][9][64];
#pragma unroll
  for (int co = 0; co < 9; ++co) red[wave][co][lane] = acc[co];
  __syncthreads();
  for (int o = tid; o < 9 * 64; o += 512) {
    const int co = o >> 6, w2 = o & 63;
    float s = mask_b[co];
#pragma unroll
    for (int w = 0; w < 8; ++w) s += red[w][co][w2];
    mask[((n * 9 + co) << 12) + (ho << 6) + w2] = 1.f / (1.f + expf(-s));
  }
}

// ---------------------------------------------------------------------------
// K3: main modulated deform conv, bf16 MFMA GEMM, channel-major K.  (= r11)
// C[256co x 16384px] = Wbf[256 x 2304] * cols[2304 x px], k = c*9 + tap.
// Block: BN=64 px (one output row), BM=256, BK=64, 512 thr = 8 waves, grid 256.
// x staged via global_load_lds into a 9-slot strip ring, 32 rows/channel in
// 8 linear 1024B (4-row) groups at 1040B stride. Params in LDS tables with
// precomputed padded byte offsets.
// ---------------------------------------------------------------------------
__device__ __forceinline__ void stage_channel_pad(const float* src, char* dstb,
                                                  int lane) {
  // 32 rows x 256B staged as 8 linear 1024B calls at 1040B LDS stride.
  const char* s = (const char*)src + lane * 16;
#pragma unroll
  for (int j = 0; j < 8; ++j)
    __builtin_amdgcn_global_load_lds(
        (const __attribute__((address_space(1))) void*)(s + j * 1024),
        (__attribute__((address_space(3))) void*)(dstb + j * 1040), 16, 0, 0);
}

__global__ __launch_bounds__(512, 2) void k_deform_gemm(
    const float* __restrict__ x, const float* __restrict__ offs,
    const float* __restrict__ mask, const unsigned short* __restrict__ wbf,
    const float* __restrict__ bias, float* __restrict__ out)
{
  __shared__ float strip[9 * 2080];                    // 9 x 8320 B = 74880 B
  __shared__ __align__(16) unsigned short Bs[64][72];  // 9216 B
  __shared__ float4 pwT[9][64];                        // 9216 B
  __shared__ int    piT[9][64];                        // 2304 B -> 95616 B

  const int tid = threadIdx.x;
  // XCD swizzle: b&7 = XCD; each XCD owns a 32-row strip of one batch.
  const int b    = blockIdx.x;            // 256 blocks
  const int xcd  = b & 7, bslot = b >> 3; // bslot 0..31
  const int n    = xcd >> 1;
  const int ho   = ((xcd & 1) << 5) + bslot;      // 0..63
  const int pxb  = ho << 6;                       // px base within batch
  const int ylo  = min(max(ho - 15, 0), 32);      // strip rows [ylo, ylo+32)

  const int pxl  = tid & 63;        // px within row (= lane)
  const int oct  = tid >> 6;        // wave id; k-octet of 8
  const int lane = tid & 63;
  const int mrow = lane & 15;
  const int koct = lane >> 4;       // 0..3 -> k-subgroup of 8
  const float* xn = x + ((long)(n << 8) << 12);
  const char* xnc = (const char*)xn;
  char* stripc = (char*)strip;

  // --- prologue: stage channels 0..7 (window of iter 0), one per wave
  stage_channel_pad(xn + (oct << 12) + (ylo << 6), stripc + oct * 8320, lane);
  int c_staged = 8;

  // --- phase 0: sampling params into LDS tables (e = tap*64 + px)
  for (int e = tid; e < 576; e += 512) {
    const int tap = e >> 6, pl = e & 63;
    const int wo = pl;
    const float dy = offs[((n * 18 + 2 * tap) << 12) + pxb + pl];
    const float dx = offs[((n * 18 + 2 * tap + 1) << 12) + pxb + pl];
    const float m  = mask[((n * 9 + tap) << 12) + pxb + pl];
    const float yy = (float)(ho - 1 + tap / 3) + dy;
    const float xx = (float)(wo - 1 + tap % 3) + dx;
    const float y0f = floorf(yy), x0f = floorf(xx);
    const float ly = yy - y0f, lx = xx - x0f;
    const int y0 = (int)y0f, x0 = (int)x0f;
    const int y0c = min(max(y0, 0), 63);
    const int y1c = min(max(y0 + 1, 0), 63);
    const float fy0 = (y0 >= 0 && y0 < 64) ? 1.f : 0.f;
    const float fy1 = (y0 >= -1 && y0 < 63) ? 1.f : 0.f;
    // horizontal pair remap: contribution = wl*p[bx] + wr*p[bx+1]
    const int x0c = min(max(x0, 0), 63);
    const int x1c = min(max(x0 + 1, 0), 63);
    const int bx  = min(max(x0, 0), 62);
    const float vx0 = (x0 >= 0 && x0 < 64) ? 1.f : 0.f;
    const float vx1 = (x0 >= -1 && x0 < 63) ? 1.f : 0.f;
    const float wl = (1.f - lx) * vx0 * ((x0c == bx) ? 1.f : 0.f)
                   + lx * vx1 * ((x1c == bx) ? 1.f : 0.f);
    const float wr = (1.f - lx) * vx0 * ((x0c == bx + 1) ? 1.f : 0.f)
                   + lx * vx1 * ((x1c == bx + 1) ? 1.f : 0.f);
    const float a0 = (1.f - ly) * fy0 * m;
    const float a1 = ly * fy1 * m;
    pwT[tap][pl] = make_float4(wl * a0, wr * a0, wl * a1, wr * a1);
    // strip-relative byte addrs in the group-padded layout + bad flag:
    // ad = (ry>>2)*1040 + (ry&3)*256 + bx*4  (max 8296 < 16384)
    const int ry0 = y0c - ylo, ry1 = y1c - ylo;
    const int ry0c = min(max(ry0, 0), 31), ry1c = min(max(ry1, 0), 31);
    const int bad = ((ry0 != ry0c) || (ry1 != ry1c)) ? 1 : 0;
    const int ad0 = (ry0c >> 2) * 1040 + (ry0c & 3) * 256 + (bx << 2);
    const int ad1 = (ry1c >> 2) * 1040 + (ry1c & 3) * 256 + (bx << 2);
    piT[tap][pl] = ad0 | (ad1 << 14) | (bad << 28);
  }
  __syncthreads();   // params + prologue strip visible (barrier drains vmcnt)

  // --- gather: one k-octet (8 k) per lane into Bs; params from LDS tables.
  auto gather = [&](int ic) {
    const int k0 = (ic << 6) + (oct << 3);
    const int c0 = (int)(((unsigned)k0 * 7282u) >> 16);    // k0/9
    int tap = k0 - 9 * c0;
    const int s9 = (int)(((unsigned)c0 * 7282u) >> 16);    // c0/9
    int soff = (c0 - 9 * s9) * 8320;                       // slot byte offset

    __align__(16) unsigned short v[8];
    unsigned badm = 0;
#pragma unroll
    for (int j = 0; j < 8; ++j) {
      const int pk  = piT[tap][pxl];              // ds_read_b32
      const float4 w = pwT[tap][pxl];             // ds_read_b128
      const float2_u A = *(const float2_u*)(stripc + soff + (pk & 16383));
      const float2_u B = *(const float2_u*)(stripc + soff + ((pk >> 14) & 16383));
      v[j] = f2bf(A.x * w.x + A.y * w.y + B.x * w.z + B.y * w.w);
      badm |= ((unsigned)pk >> 28) << j;          // bit28 = bad; bits 29-31 = 0
      if (++tap == 9) {
        tap = 0;
        soff += 8320; if (soff == 9 * 8320) soff = 0;
      }
    }

    if (__builtin_expect(badm != 0, 0)) {         // ~10 events per launch
#pragma unroll
      for (int j = 0; j < 8; ++j) if (badm & (1u << j)) {
        const int k = k0 + j;
        const int c = (int)(((unsigned)k * 7282u) >> 16);
        const int tp = k - 9 * c;
        // full recompute from global (identical math to phase 0)
        const float dy = offs[((n * 18 + 2 * tp) << 12) + pxb + pxl];
        const float dx = offs[((n * 18 + 2 * tp + 1) << 12) + pxb + pxl];
        const float m  = mask[((n * 9 + tp) << 12) + pxb + pxl];
        const float yy = (float)(ho - 1 + tp / 3) + dy;
        const float xx = (float)(pxl - 1 + tp % 3) + dx;
        const float y0f = floorf(yy), x0f = floorf(xx);
        const float ly = yy - y0f, lx = xx - x0f;
        const int y0 = (int)y0f, x0 = (int)x0f;
        const int y0c = min(max(y0, 0), 63);
        const int y1c = min(max(y0 + 1, 0), 63);
        const float fy0 = (y0 >= 0 && y0 < 64) ? 1.f : 0.f;
        const float fy1 = (y0 >= -1 && y0 < 63) ? 1.f : 0.f;
        const int x0c = min(max(x0, 0), 63);
        const int x1c = min(max(x0 + 1, 0), 63);
        const int bx  = min(max(x0, 0), 62);
        const float vx0 = (x0 >= 0 && x0 < 64) ? 1.f : 0.f;
        const float vx1 = (x0 >= -1 && x0 < 63) ? 1.f : 0.f;
        const float wl = (1.f - lx) * vx0 * ((x0c == bx) ? 1.f : 0.f)
                       + lx * vx1 * ((x1c == bx) ? 1.f : 0.f);
        const float wr = (1.f - lx) * vx0 * ((x0c == bx + 1) ? 1.f : 0.f)
                       + lx * vx1 * ((x1c == bx + 1) ? 1.f : 0.f);
        const float a0 = (1.f - ly) * fy0 * m;
        const float a1 = ly * fy1 * m;
        const char* pg = xnc + ((long)c << 14);
        const float2_u Ag = *(const float2_u*)(pg + (((y0c << 6) + bx) << 2));
        const float2_u Bg = *(const float2_u*)(pg + (((y1c << 6) + bx) << 2));
        v[j] = f2bf(Ag.x * (wl * a0) + Ag.y * (wr * a0) +
                    Bg.x * (wl * a1) + Bg.y * (wr * a1));
      }
    }
    *(int4*)&Bs[pxl][oct << 3] = *(const int4*)v;
  };

  // A-fragment prefetch registers for iter 0
  bf16x8 afc[2][2];
#pragma unroll
  for (int mt = 0; mt < 2; ++mt)
#pragma unroll
    for (int ks = 0; ks < 2; ++ks) {
      const int row = (oct << 5) + (mt << 4) + mrow;
      const int col = (ks << 5) + (koct << 3);
      afc[mt][ks] = *(const bf16x8*)(wbf + row * 2304 + col);
    }

  gather(0);
  __syncthreads();

  f32x4 acc[2][4];
#pragma unroll
  for (int mt = 0; mt < 2; ++mt)
#pragma unroll
    for (int nt = 0; nt < 4; ++nt)
#pragma unroll
      for (int r = 0; r < 4; ++r) acc[mt][nt][r] = 0.f;

  for (int ic = 0; ic < 36; ++ic) {
    // phase 1: stage next window (global_load_lds, overlaps MFMA; drained at
    // the barrier) + prefetch af(ic+1), MFMA(ic), barrier, gather(ic+1), barrier.
    if (ic < 35) {
      const int c_end = (64 * ic + 127) / 9;          // c_hi(ic+1) <= 255
      const int cw = c_staged + oct;
      if (cw <= c_end) {
        const int slt = cw - 9 * (int)(((unsigned)cw * 7282u) >> 16);
        stage_channel_pad(xn + (cw << 12) + (ylo << 6),
                          stripc + slt * 8320, lane);
      }
      c_staged = c_end + 1;
    }

    bf16x8 afn[2][2];
    if (ic < 35) {
      const int kc = (ic + 1) << 6;
#pragma unroll
      for (int mt = 0; mt < 2; ++mt)
#pragma unroll
        for (int ks = 0; ks < 2; ++ks) {
          const int row = (oct << 5) + (mt << 4) + mrow;
          const int col = kc + (ks << 5) + (koct << 3);
          afn[mt][ks] = *(const bf16x8*)(wbf + row * 2304 + col);
        }
    }

#pragma unroll
    for (int ks = 0; ks < 2; ++ks)
#pragma unroll
      for (int nt = 0; nt < 4; ++nt) {
        const bf16x8 bfr =
            *(const bf16x8*)&Bs[(nt << 4) + mrow][(ks << 5) + (koct << 3)];
        acc[0][nt] = __builtin_amdgcn_mfma_f32_16x16x32_bf16(afc[0][ks], bfr,
                                                             acc[0][nt], 0, 0, 0);
        acc[1][nt] = __builtin_amdgcn_mfma_f32_16x16x32_bf16(afc[1][ks], bfr,
                                                             acc[1][nt], 0, 0, 0);
      }

    __syncthreads();           // drains stage; Bs free for rewrite
    if (ic < 35) gather(ic + 1);
    __syncthreads();           // Bs ready for next MFMA; strip safe to restage

#pragma unroll
    for (int mt = 0; mt < 2; ++mt)
#pragma unroll
      for (int ks = 0; ks < 2; ++ks) afc[mt][ks] = afn[mt][ks];
  }

  // epilogue: C/D layout col=lane&15 (px), row=(lane>>4)*4+r (co)
#pragma unroll
  for (int mt = 0; mt < 2; ++mt)
#pragma unroll
    for (int nt = 0; nt < 4; ++nt)
#pragma unroll
      for (int r = 0; r < 4; ++r) {
        const int co = (oct << 5) + (mt << 4) + ((lane >> 4) << 2) + r;
        const int pxg = pxb + (nt << 4) + (lane & 15);
        out[(((n << 8) + co) << 12) + pxg] = acc[mt][nt][r] + bias[co];
      }
}

// ---------------------------------------------------------------------------
extern "C" void kernel_launch(void* const* d_in, const int* in_sizes, int n_in,
                              void* d_out, int out_size, void* d_ws, size_t ws_size,
                              hipStream_t stream) {
  const float* x      = (const float*)d_in[0];
  const float* depth  = (const float*)d_in[1];
  const float* weight = (const float*)d_in[2];
  const float* bias   = (const float*)d_in[3];
  const float* off_w  = (const float*)d_in[4];
  const float* off_b  = (const float*)d_in[5];
  const float* mask_w = (const float*)d_in[6];
  const float* mask_b = (const float*)d_in[7];
  float* out = (float*)d_out;

  float* offs = (float*)d_ws;                       // 294912 floats
  float* mask = offs + 294912;                      // 147456 floats
  unsigned short* wbf = (unsigned short*)(mask + 147456);  // 589824 bf16

  hipMemsetAsync(offs, 0, 294912 * sizeof(float), stream);
  k_prep_weight<<<2304, 256, 0, stream>>>(weight, wbf);
  k_offset_conv<<<1024, 256, 0, stream>>>(x, depth, off_w, off_b, offs);
  k_mask_conv<<<256, 512, 0, stream>>>(depth, offs, mask_w, mask_b, mask);
  k_deform_gemm<<<256, 512, 0, stream>>>(x, offs, mask, wbf, bias, out);
}

// Round 10
// 243.706 us; speedup vs baseline: 1.0941x; 1.0060x over previous
//
#include <hip/hip_runtime.h>

// DepthDeformConvPack on MI355X — round 14: per-ROW bank rotation in K3.
// r13 post-mortem (245us best; K3=103.6): r11's conflict-padding null is
// explained by GRANULARITY: its 1024B calls pad at 4-row boundaries, so
// same-bank collisions with drow in {1,2,3} (the common case at sigma~2.7)
// kept identical bank shifts. Fix legal under global_load_lds rules:
// size=4 calls write exactly ONE 256B row (64 lanes x 4B, linear), so 32
// calls at 272B LDS stride give bank = (4*row + bx) % 32 -> every drow in
// 1..7 rotates banks. Cost ~+100cy/wave/iter staging issues vs up to
// 173cy/wave-gather conflicts reclaimed. K3-only change vs r13 (K0/K1/K2
// byte-identical); piT packs ad = ry*272 + bx*4 (<= 8680 < 2^14).
// Decisive readout: SQ_LDS_BANK_CONFLICT 12.66M -> <=5M predicted; if
// unchanged, the bank model of the strip reads is refuted (3 strikes) and
// next round pivots to the non-K3 ~141us (K1 atomics, K0 fusion, memset).

typedef __bf16 bf16x8 __attribute__((ext_vector_type(8)));
typedef float f32x4 __attribute__((ext_vector_type(4)));
typedef float float2_u __attribute__((ext_vector_type(2), aligned(4)));

__device__ __forceinline__ unsigned short f2bf(float f) {
  unsigned b = __float_as_uint(f);
  return (unsigned short)((b + 0x7fffu + ((b >> 16) & 1u)) >> 16);
}

// ---------------------------------------------------------------------------
// K0: weight fp32 -> bf16, natural layout (k = c*9+tap is already channel-major)
// ---------------------------------------------------------------------------
__global__ __launch_bounds__(256) void k_prep_weight(
    const float* __restrict__ w, unsigned short* __restrict__ wbf)
{
  const int i = blockIdx.x * 256 + threadIdx.x;   // grid 2304 -> 589824
  wbf[i] = f2bf(w[i]);
}

// ---------------------------------------------------------------------------
// K1: offset conv. grid = 4 ch-segments x (n,ho)=256 -> 1024 blocks, 256 thr.
// ---------------------------------------------------------------------------
__global__ __launch_bounds__(256) void k_offset_conv(
    const float* __restrict__ x, const float* __restrict__ depth,
    const float* __restrict__ off_w, const float* __restrict__ off_b,
    float* __restrict__ offs)
{
  const int seg = blockIdx.x >> 8;        // 0..3
  const int nh  = blockIdx.x & 255;
  const int n = nh >> 6, ho = nh & 63;
  const int tid = threadIdx.x;
  const int lane = tid & 63;              // == wo
  const int wave = tid >> 6;

  float acc[18];
#pragma unroll
  for (int i = 0; i < 18; ++i) acc[i] = 0.f;

  const int c0 = __builtin_amdgcn_readfirstlane(seg * 80 + wave * 20);

  for (int ci = 0; ci < 20; ++ci) {
    const int c = c0 + ci;
    const float* p = (c < 256) ? (x + (((n << 8) + c) << 12))
                               : (depth + (((n << 6) + (c - 256)) << 12));
    const float v0 = (ho > 0)  ? p[((ho - 1) << 6) + lane] : 0.f;
    const float v1 =             p[( ho      << 6) + lane];
    const float v2 = (ho < 63) ? p[((ho + 1) << 6) + lane] : 0.f;

    float v[9];
#pragma unroll
    for (int ky = 0; ky < 3; ++ky) {
      const float r = (ky == 0) ? v0 : ((ky == 1) ? v1 : v2);
#pragma unroll
      for (int kx = 0; kx < 3; ++kx) {
        const int src = lane + kx - 1;
        const float s = __shfl(r, src & 63);
        v[ky * 3 + kx] = (src >= 0 && src < 64) ? s : 0.f;
      }
    }
    const float* wp = off_w + c * 9;   // wave-uniform address
#pragma unroll
    for (int co = 0; co < 18; ++co) {
      const float* w = wp + co * 2880;
#pragma unroll
      for (int t = 0; t < 9; ++t) acc[co] += v[t] * w[t];
    }
  }

  __shared__ float red[4][18][64];
#pragma unroll
  for (int co = 0; co < 18; ++co) red[wave][co][lane] = acc[co];
  __syncthreads();
  for (int o = tid; o < 18 * 64; o += 256) {
    const int co = o >> 6, wo = o & 63;
    float s = red[0][co][wo] + red[1][co][wo] + red[2][co][wo] + red[3][co][wo];
    if (seg == 0) s += off_b[co];
    atomicAdd(&offs[((n * 18 + co) << 12) + (ho << 6) + wo], s);
  }
}

// ---------------------------------------------------------------------------
// K2: mask deform conv on depth + sigmoid. 256 blocks (n,ho), 512 thr = 8 waves.
// Pair-load gather: per tap, 2x float2_u row-pair loads with folded weights.
// ---------------------------------------------------------------------------
__global__ __launch_bounds__(512) void k_mask_conv(
    const float* __restrict__ depth, const float* __restrict__ offs,
    const float* __restrict__ mask_w, const float* __restrict__ mask_b,
    float* __restrict__ mask)
{
  const int n  = blockIdx.x >> 6;
  const int ho = blockIdx.x & 63;
  const int tid  = threadIdx.x;
  const int lane = tid & 63;          // wo
  const int wave = tid >> 6;          // 0..7
  const int wo = lane;

  int ia[9], ib[9];
  float w0[9], w1[9], w2c[9], w3[9];
  const float* op = offs + ((n * 18) << 12) + (ho << 6) + wo;
#pragma unroll
  for (int k = 0; k < 9; ++k) {
    const float dy = op[(2 * k) << 12];
    const float dx = op[(2 * k + 1) << 12];
    const float yy = (float)(ho - 1 + k / 3) + dy;
    const float xx = (float)(wo - 1 + k % 3) + dx;
    const float y0f = floorf(yy), x0f = floorf(xx);
    const float ly = yy - y0f, lx = xx - x0f;
    const int y0 = (int)y0f, x0 = (int)x0f;
    const int y0c = min(max(y0, 0), 63);
    const int y1c = min(max(y0 + 1, 0), 63);
    const float fy0 = (y0 >= 0 && y0 < 64) ? 1.f : 0.f;
    const float fy1 = (y0 >= -1 && y0 < 63) ? 1.f : 0.f;
    // horizontal pair remap (K3-proven): contribution = wl*p[bx] + wr*p[bx+1]
    const int x0c = min(max(x0, 0), 63);
    const int x1c = min(max(x0 + 1, 0), 63);
    const int bx  = min(max(x0, 0), 62);
    const float vx0 = (x0 >= 0 && x0 < 64) ? 1.f : 0.f;
    const float vx1 = (x0 >= -1 && x0 < 63) ? 1.f : 0.f;
    const float wl = (1.f - lx) * vx0 * ((x0c == bx) ? 1.f : 0.f)
                   + lx * vx1 * ((x1c == bx) ? 1.f : 0.f);
    const float wr = (1.f - lx) * vx0 * ((x0c == bx + 1) ? 1.f : 0.f)
                   + lx * vx1 * ((x1c == bx + 1) ? 1.f : 0.f);
    const float a0 = (1.f - ly) * fy0;
    const float a1 = ly * fy1;
    ia[k] = ((y0c << 6) + bx) << 2;     // byte offsets
    ib[k] = ((y1c << 6) + bx) << 2;
    w0[k] = wl * a0;  w1[k] = wr * a0;
    w2c[k] = wl * a1; w3[k] = wr * a1;
  }

  float acc[9];
#pragma unroll
  for (int i = 0; i < 9; ++i) acc[i] = 0.f;

  const int cbase = __builtin_amdgcn_readfirstlane(wave * 8);
  for (int cc = 0; cc < 8; ++cc) {
    const int c = cbase + cc;
    const char* p = (const char*)(depth + (((n << 6) + c) << 12));
    float val[9];
#pragma unroll
    for (int k = 0; k < 9; ++k) {
      const float2_u A = *(const float2_u*)(p + ia[k]);
      const float2_u B = *(const float2_u*)(p + ib[k]);
      val[k] = A.x * w0[k] + A.y * w1[k] + B.x * w2c[k] + B.y * w3[k];
    }
    const float* wp = mask_w + c * 9;
#pragma unroll
    for (int co = 0; co < 9; ++co) {
#pragma unroll
      for (int k = 0; k < 9; ++k) acc[co] += val[k] * wp[co * 576 + k];
    }
  }

  __shared__ float red[8][9][64];
#pragma unroll
  for (int co = 0; co < 9; ++co) red[wave][co][lane] = acc[co];
  __syncthreads();
  for (int o = tid; o < 9 * 64; o += 512) {
    const int co = o >> 6, w2 = o & 63;
    float s = mask_b[co];
#pragma unroll
    for (int w = 0; w < 8; ++w) s += red[w][co][w2];
    mask[((n * 9 + co) << 12) + (ho << 6) + w2] = 1.f / (1.f + expf(-s));
  }
}

// ---------------------------------------------------------------------------
// K3: main modulated deform conv, bf16 MFMA GEMM, channel-major K.
// C[256co x 16384px] = Wbf[256 x 2304] * cols[2304 x px], k = c*9 + tap.
// Block: BN=64 px (one output row), BM=256, BK=64, 512 thr = 8 waves, grid 256.
// x staged via 32x size-4 global_load_lds calls per channel (one 256B row
// each) at 272B LDS stride -> bank = (4*row + bx) % 32, per-row rotation.
// Params in LDS tables with precomputed padded byte offsets.
// ---------------------------------------------------------------------------
__device__ __forceinline__ void stage_channel_row(const float* src, char* dstb,
                                                  int lane) {
  // 32 rows x 256B; each size-4 call writes one row (64 lanes x 4B, linear).
  const char* s = (const char*)src + lane * 4;
#pragma unroll
  for (int j = 0; j < 32; ++j)
    __builtin_amdgcn_global_load_lds(
        (const __attribute__((address_space(1))) void*)(s + j * 256),
        (__attribute__((address_space(3))) void*)(dstb + j * 272), 4, 0, 0);
}

__global__ __launch_bounds__(512, 2) void k_deform_gemm(
    const float* __restrict__ x, const float* __restrict__ offs,
    const float* __restrict__ mask, const unsigned short* __restrict__ wbf,
    const float* __restrict__ bias, float* __restrict__ out)
{
  __shared__ float strip[9 * 2176];                    // 9 x 8704 B = 78336 B
  __shared__ __align__(16) unsigned short Bs[64][72];  // 9216 B
  __shared__ float4 pwT[9][64];                        // 9216 B
  __shared__ int    piT[9][64];                        // 2304 B -> 99072 B

  const int tid = threadIdx.x;
  // XCD swizzle: b&7 = XCD; each XCD owns a 32-row strip of one batch.
  const int b    = blockIdx.x;            // 256 blocks
  const int xcd  = b & 7, bslot = b >> 3; // bslot 0..31
  const int n    = xcd >> 1;
  const int ho   = ((xcd & 1) << 5) + bslot;      // 0..63
  const int pxb  = ho << 6;                       // px base within batch
  const int ylo  = min(max(ho - 15, 0), 32);      // strip rows [ylo, ylo+32)

  const int pxl  = tid & 63;        // px within row (= lane)
  const int oct  = tid >> 6;        // wave id; k-octet of 8
  const int lane = tid & 63;
  const int mrow = lane & 15;
  const int koct = lane >> 4;       // 0..3 -> k-subgroup of 8
  const float* xn = x + ((long)(n << 8) << 12);
  const char* xnc = (const char*)xn;
  char* stripc = (char*)strip;

  // --- prologue: stage channels 0..7 (window of iter 0), one per wave
  stage_channel_row(xn + (oct << 12) + (ylo << 6), stripc + oct * 8704, lane);
  int c_staged = 8;

  // --- phase 0: sampling params into LDS tables (e = tap*64 + px)
  for (int e = tid; e < 576; e += 512) {
    const int tap = e >> 6, pl = e & 63;
    const int wo = pl;
    const float dy = offs[((n * 18 + 2 * tap) << 12) + pxb + pl];
    const float dx = offs[((n * 18 + 2 * tap + 1) << 12) + pxb + pl];
    const float m  = mask[((n * 9 + tap) << 12) + pxb + pl];
    const float yy = (float)(ho - 1 + tap / 3) + dy;
    const float xx = (float)(wo - 1 + tap % 3) + dx;
    const float y0f = floorf(yy), x0f = floorf(xx);
    const float ly = yy - y0f, lx = xx - x0f;
    const int y0 = (int)y0f, x0 = (int)x0f;
    const int y0c = min(max(y0, 0), 63);
    const int y1c = min(max(y0 + 1, 0), 63);
    const float fy0 = (y0 >= 0 && y0 < 64) ? 1.f : 0.f;
    const float fy1 = (y0 >= -1 && y0 < 63) ? 1.f : 0.f;
    // horizontal pair remap: contribution = wl*p[bx] + wr*p[bx+1]
    const int x0c = min(max(x0, 0), 63);
    const int x1c = min(max(x0 + 1, 0), 63);
    const int bx  = min(max(x0, 0), 62);
    const float vx0 = (x0 >= 0 && x0 < 64) ? 1.f : 0.f;
    const float vx1 = (x0 >= -1 && x0 < 63) ? 1.f : 0.f;
    const float wl = (1.f - lx) * vx0 * ((x0c == bx) ? 1.f : 0.f)
                   + lx * vx1 * ((x1c == bx) ? 1.f : 0.f);
    const float wr = (1.f - lx) * vx0 * ((x0c == bx + 1) ? 1.f : 0.f)
                   + lx * vx1 * ((x1c == bx + 1) ? 1.f : 0.f);
    const float a0 = (1.f - ly) * fy0 * m;
    const float a1 = ly * fy1 * m;
    pwT[tap][pl] = make_float4(wl * a0, wr * a0, wl * a1, wr * a1);
    // strip-relative byte addrs in the row-rotated layout + bad flag:
    // ad = ry*272 + bx*4  (max 8680 < 16384)
    const int ry0 = y0c - ylo, ry1 = y1c - ylo;
    const int ry0c = min(max(ry0, 0), 31), ry1c = min(max(ry1, 0), 31);
    const int bad = ((ry0 != ry0c) || (ry1 != ry1c)) ? 1 : 0;
    const int ad0 = ry0c * 272 + (bx << 2);
    const int ad1 = ry1c * 272 + (bx << 2);
    piT[tap][pl] = ad0 | (ad1 << 14) | (bad << 28);
  }
  __syncthreads();   // params + prologue strip visible (barrier drains vmcnt)

  // --- gather: one k-octet (8 k) per lane into Bs; params from LDS tables.
  auto gather = [&](int ic) {
    const int k0 = (ic << 6) + (oct << 3);
    const int c0 = (int)(((unsigned)k0 * 7282u) >> 16);    // k0/9
    int tap = k0 - 9 * c0;
    const int s9 = (int)(((unsigned)c0 * 7282u) >> 16);    // c0/9
    int soff = (c0 - 9 * s9) * 8704;                       // slot byte offset

    __align__(16) unsigned short v[8];
    unsigned badm = 0;
#pragma unroll
    for (int j = 0; j < 8; ++j) {
      const int pk  = piT[tap][pxl];              // ds_read_b32
      const float4 w = pwT[tap][pxl];             // ds_read_b128
      const float2_u A = *(const float2_u*)(stripc + soff + (pk & 16383));
      const float2_u B = *(const float2_u*)(stripc + soff + ((pk >> 14) & 16383));
      v[j] = f2bf(A.x * w.x + A.y * w.y + B.x * w.z + B.y * w.w);
      badm |= ((unsigned)pk >> 28) << j;          // bit28 = bad; bits 29-31 = 0
      if (++tap == 9) {
        tap = 0;
        soff += 8704; if (soff == 9 * 8704) soff = 0;
      }
    }

    if (__builtin_expect(badm != 0, 0)) {         // ~10 events per launch
#pragma unroll
      for (int j = 0; j < 8; ++j) if (badm & (1u << j)) {
        const int k = k0 + j;
        const int c = (int)(((unsigned)k * 7282u) >> 16);
        const int tp = k - 9 * c;
        // full recompute from global (identical math to phase 0)
        const float dy = offs[((n * 18 + 2 * tp) << 12) + pxb + pxl];
        const float dx = offs[((n * 18 + 2 * tp + 1) << 12) + pxb + pxl];
        const float m  = mask[((n * 9 + tp) << 12) + pxb + pxl];
        const float yy = (float)(ho - 1 + tp / 3) + dy;
        const float xx = (float)(pxl - 1 + tp % 3) + dx;
        const float y0f = floorf(yy), x0f = floorf(xx);
        const float ly = yy - y0f, lx = xx - x0f;
        const int y0 = (int)y0f, x0 = (int)x0f;
        const int y0c = min(max(y0, 0), 63);
        const int y1c = min(max(y0 + 1, 0), 63);
        const float fy0 = (y0 >= 0 && y0 < 64) ? 1.f : 0.f;
        const float fy1 = (y0 >= -1 && y0 < 63) ? 1.f : 0.f;
        const int x0c = min(max(x0, 0), 63);
        const int x1c = min(max(x0 + 1, 0), 63);
        const int bx  = min(max(x0, 0), 62);
        const float vx0 = (x0 >= 0 && x0 < 64) ? 1.f : 0.f;
        const float vx1 = (x0 >= -1 && x0 < 63) ? 1.f : 0.f;
        const float wl = (1.f - lx) * vx0 * ((x0c == bx) ? 1.f : 0.f)
                       + lx * vx1 * ((x1c == bx) ? 1.f : 0.f);
        const float wr = (1.f - lx) * vx0 * ((x0c == bx + 1) ? 1.f : 0.f)
                       + lx * vx1 * ((x1c == bx + 1) ? 1.f : 0.f);
        const float a0 = (1.f - ly) * fy0 * m;
        const float a1 = ly * fy1 * m;
        const char* pg = xnc + ((long)c << 14);
        const float2_u Ag = *(const float2_u*)(pg + (((y0c << 6) + bx) << 2));
        const float2_u Bg = *(const float2_u*)(pg + (((y1c << 6) + bx) << 2));
        v[j] = f2bf(Ag.x * (wl * a0) + Ag.y * (wr * a0) +
                    Bg.x * (wl * a1) + Bg.y * (wr * a1));
      }
    }
    *(int4*)&Bs[pxl][oct << 3] = *(const int4*)v;
  };

  // A-fragment prefetch registers for iter 0
  bf16x8 afc[2][2];
#pragma unroll
  for (int mt = 0; mt < 2; ++mt)
#pragma unroll
    for (int ks = 0; ks < 2; ++ks) {
      const int row = (oct << 5) + (mt << 4) + mrow;
      const int col = (ks << 5) + (koct << 3);
      afc[mt][ks] = *(const bf16x8*)(wbf + row * 2304 + col);
    }

  gather(0);
  __syncthreads();

  f32x4 acc[2][4];
#pragma unroll
  for (int mt = 0; mt < 2; ++mt)
#pragma unroll
    for (int nt = 0; nt < 4; ++nt)
#pragma unroll
      for (int r = 0; r < 4; ++r) acc[mt][nt][r] = 0.f;

  for (int ic = 0; ic < 36; ++ic) {
    // phase 1: stage next window (global_load_lds, overlaps MFMA; drained at
    // the barrier) + prefetch af(ic+1), MFMA(ic), barrier, gather(ic+1), barrier.
    if (ic < 35) {
      const int c_end = (64 * ic + 127) / 9;          // c_hi(ic+1) <= 255
      const int cw = c_staged + oct;
      if (cw <= c_end) {
        const int slt = cw - 9 * (int)(((unsigned)cw * 7282u) >> 16);
        stage_channel_row(xn + (cw << 12) + (ylo << 6),
                          stripc + slt * 8704, lane);
      }
      c_staged = c_end + 1;
    }

    bf16x8 afn[2][2];
    if (ic < 35) {
      const int kc = (ic + 1) << 6;
#pragma unroll
      for (int mt = 0; mt < 2; ++mt)
#pragma unroll
        for (int ks = 0; ks < 2; ++ks) {
          const int row = (oct << 5) + (mt << 4) + mrow;
          const int col = kc + (ks << 5) + (koct << 3);
          afn[mt][ks] = *(const bf16x8*)(wbf + row * 2304 + col);
        }
    }

#pragma unroll
    for (int ks = 0; ks < 2; ++ks)
#pragma unroll
      for (int nt = 0; nt < 4; ++nt) {
        const bf16x8 bfr =
            *(const bf16x8*)&Bs[(nt << 4) + mrow][(ks << 5) + (koct << 3)];
        acc[0][nt] = __builtin_amdgcn_mfma_f32_16x16x32_bf16(afc[0][ks], bfr,
                                                             acc[0][nt], 0, 0, 0);
        acc[1][nt] = __builtin_amdgcn_mfma_f32_16x16x32_bf16(afc[1][ks], bfr,
                                                             acc[1][nt], 0, 0, 0);
      }

    __syncthreads();           // drains stage; Bs free for rewrite
    if (ic < 35) gather(ic + 1);
    __syncthreads();           // Bs ready for next MFMA; strip safe to restage

#pragma unroll
    for (int mt = 0; mt < 2; ++mt)
#pragma unroll
      for (int ks = 0; ks < 2; ++ks) afc[mt][ks] = afn[mt][ks];
  }

  // epilogue: C/D layout col=lane&15 (px), row=(lane>>4)*4+r (co)
#pragma unroll
  for (int mt = 0; mt < 2; ++mt)
#pragma unroll
    for (int nt = 0; nt < 4; ++nt)
#pragma unroll
      for (int r = 0; r < 4; ++r) {
        const int co = (oct << 5) + (mt << 4) + ((lane >> 4) << 2) + r;
        const int pxg = pxb + (nt << 4) + (lane & 15);
        out[(((n << 8) + co) << 12) + pxg] = acc[mt][nt][r] + bias[co];
      }
}

// ---------------------------------------------------------------------------
extern "C" void kernel_launch(void* const* d_in, const int* in_sizes, int n_in,
                              void* d_out, int out_size, void* d_ws, size_t ws_size,
                              hipStream_t stream) {
  const float* x      = (const float*)d_in[0];
  const float* depth  = (const float*)d_in[1];
  const float* weight = (const float*)d_in[2];
  const float* bias   = (const float*)d_in[3];
  const float* off_w  = (const float*)d_in[4];
  const float* off_b  = (const float*)d_in[5];
  const float* mask_w = (const float*)d_in[6];
  const float* mask_b = (const float*)d_in[7];
  float* out = (float*)d_out;

  float* offs = (float*)d_ws;                       // 294912 floats
  float* mask = offs + 294912;                      // 147456 floats
  unsigned short* wbf = (unsigned short*)(mask + 147456);  // 589824 bf16

  hipMemsetAsync(offs, 0, 294912 * sizeof(float), stream);
  k_prep_weight<<<2304, 256, 0, stream>>>(weight, wbf);
  k_offset_conv<<<1024, 256, 0, stream>>>(x, depth, off_w, off_b, offs);
  k_mask_conv<<<256, 512, 0, stream>>>(depth, offs, mask_w, mask_b, mask);
  k_deform_gemm<<<256, 512, 0, stream>>>(x, offs, mask, wbf, bias, out);
}